// Round 1
// baseline (22839.143 us; speedup 1.0000x reference)
//
#include <hip/hip_runtime.h>

#define NN 50000
#define NE 800000
#define KH 4
#define FIN 6
#define FH 128
#define FO 6
#define ADIM 3

// ---------------- degree + norm ----------------
__global__ void deg_kernel(const int* __restrict__ col, const float* __restrict__ w,
                           float* __restrict__ deg) {
    int e = blockIdx.x * blockDim.x + threadIdx.x;
    if (e < NE) atomicAdd(&deg[col[e]], w[e]);
}

__global__ void normw_kernel(const int* __restrict__ row, const int* __restrict__ col,
                             const float* __restrict__ w, const float* __restrict__ deg,
                             float* __restrict__ nw) {
    int e = blockIdx.x * blockDim.x + threadIdx.x;
    if (e >= NE) return;
    float dr = deg[row[e]];
    float dc = deg[col[e]];
    float ir = dr > 0.f ? rsqrtf(dr) : 0.f;
    float ic = dc > 0.f ? rsqrtf(dc) : 0.f;
    nw[e] = ir * w[e] * ic;
}

// ---------------- layer 1: dense 6 -> 128 (acc += xk @ Wk) ----------------
__global__ void dense_6_128(const float* __restrict__ xk, const float* __restrict__ Wk,
                            float* __restrict__ acc, int init) {
    __shared__ float sW[FIN * FH]; // 768 floats
    for (int t = threadIdx.x; t < FIN * FH; t += blockDim.x) sW[t] = Wk[t];
    __syncthreads();
    int idx = blockIdx.x * blockDim.x + threadIdx.x;
    if (idx >= NN * FH) return;
    int i = idx >> 7;       // node
    int f = idx & 127;      // out channel
    const float* xr = xk + i * FIN;
    float s = 0.f;
#pragma unroll
    for (int c = 0; c < FIN; ++c) s += xr[c] * sW[c * FH + f];
    if (init) acc[idx] = s;
    else      acc[idx] += s;
}

// ---------------- hop for 6-wide features (scatter-add) ----------------
__global__ void hop6(const int* __restrict__ row, const int* __restrict__ col,
                     const float* __restrict__ nw, const float* __restrict__ xprev,
                     float* __restrict__ xnext) {
    int e = blockIdx.x * blockDim.x + threadIdx.x;
    if (e >= NE) return;
    int r = row[e], c = col[e];
    float w = nw[e];
    const float* src = xprev + r * FIN;
    float* dst = xnext + c * FIN;
#pragma unroll
    for (int j = 0; j < FIN; ++j) atomicAdd(dst + j, w * src[j]);
}

// ---------------- bias + relu in place ----------------
__global__ void bias_relu(float* __restrict__ acc, const float* __restrict__ b) {
    int idx = blockIdx.x * blockDim.x + threadIdx.x;
    if (idx >= NN * FH) return;
    int f = idx & 127;
    float v = acc[idx] + b[f];
    acc[idx] = v > 0.f ? v : 0.f;
}

// ---------------- layer 2: dense 128 -> 6 (acc += xk @ Wk) ----------------
__global__ void dense_128_6(const float* __restrict__ xk, const float* __restrict__ Wk,
                            float* __restrict__ acc, int init) {
    __shared__ float sW[FH * FO]; // 768 floats
    for (int t = threadIdx.x; t < FH * FO; t += blockDim.x) sW[t] = Wk[t];
    __syncthreads();
    int idx = blockIdx.x * blockDim.x + threadIdx.x;
    if (idx >= NN * FO) return;
    int i = idx / FO;
    int a = idx % FO;
    const float* xr = xk + i * FH;
    float s = 0.f;
#pragma unroll 8
    for (int c = 0; c < FH; ++c) s += xr[c] * sW[c * FO + a];
    if (init) acc[idx] = s;
    else      acc[idx] += s;
}

// ---------------- hop for 128-wide features (4 threads / edge) ----------------
__global__ void hop128(const int* __restrict__ row, const int* __restrict__ col,
                       const float* __restrict__ nw, const float* __restrict__ xprev,
                       float* __restrict__ xnext) {
    int t = blockIdx.x * blockDim.x + threadIdx.x;
    int e = t >> 2;    // 4 threads per edge
    int q = t & 3;     // quarter (32 channels)
    if (e >= NE) return;
    int r = row[e], c = col[e];
    float w = nw[e];
    const float4* src = (const float4*)(xprev + r * FH + q * 32);
    float* dst = xnext + c * FH + q * 32;
#pragma unroll
    for (int v = 0; v < 8; ++v) {
        float4 x4 = src[v];
        atomicAdd(dst + v * 4 + 0, w * x4.x);
        atomicAdd(dst + v * 4 + 1, w * x4.y);
        atomicAdd(dst + v * 4 + 2, w * x4.z);
        atomicAdd(dst + v * 4 + 3, w * x4.w);
    }
}

// ---------------- finalize: bias2 + tanh / exp split ----------------
__global__ void finalize(const float* __restrict__ out2, const float* __restrict__ b2,
                         float* __restrict__ out) {
    int idx = blockIdx.x * blockDim.x + threadIdx.x;
    if (idx >= NN * FO) return;
    int i = idx / FO;
    int a = idx % FO;
    float v = tanhf(out2[idx] + b2[a]);
    if (a < ADIM) out[i * ADIM + a] = v;                       // mu
    else          out[NN * ADIM + i * ADIM + (a - ADIM)] = expf(2.f * v); // sigma
}

extern "C" void kernel_launch(void* const* d_in, const int* in_sizes, int n_in,
                              void* d_out, int out_size, void* d_ws, size_t ws_size,
                              hipStream_t stream) {
    const float* x  = (const float*)d_in[0];
    const int*   ei = (const int*)d_in[1];
    const float* ew = (const float*)d_in[2];
    const float* W1 = (const float*)d_in[3];
    const float* b1 = (const float*)d_in[4];
    const float* W2 = (const float*)d_in[5];
    const float* b2 = (const float*)d_in[6];
    float* out = (float*)d_out;

    const int* row = ei;          // edge_index[0]
    const int* col = ei + NE;     // edge_index[1]

    float* ws   = (float*)d_ws;
    float* deg  = ws;                    // NN
    float* nw   = deg  + NN;             // NE
    float* acc1 = nw   + NE;             // NN*FH  (h after relu, in place)
    float* xk1a = acc1 + (size_t)NN * FH;      // NN*FIN
    float* xk1b = xk1a + (size_t)NN * FIN;     // NN*FIN
    float* xk2a = xk1b + (size_t)NN * FIN;     // NN*FH
    float* xk2b = xk2a + (size_t)NN * FH;      // NN*FH
    float* out2 = xk2b + (size_t)NN * FH;      // NN*FO

    const int B = 256;
    const int gE   = (NE + B - 1) / B;
    const int gNH  = (NN * FH + B - 1) / B;
    const int gNO  = (NN * FO + B - 1) / B;
    const int gE4  = (NE * 4 + B - 1) / B;

    // norm
    hipMemsetAsync(deg, 0, (size_t)NN * sizeof(float), stream);
    deg_kernel<<<gE, B, 0, stream>>>(col, ew, deg);
    normw_kernel<<<gE, B, 0, stream>>>(row, col, ew, deg, nw);

    // ---- layer 1 ----
    dense_6_128<<<gNH, B, 0, stream>>>(x, W1, acc1, 1);
    {
        const float* xprev = x;
        float* bufs[2] = {xk1a, xk1b};
        for (int k = 1; k <= KH; ++k) {
            float* xn = bufs[(k - 1) & 1];
            hipMemsetAsync(xn, 0, (size_t)NN * FIN * sizeof(float), stream);
            hop6<<<gE, B, 0, stream>>>(row, col, nw, xprev, xn);
            dense_6_128<<<gNH, B, 0, stream>>>(xn, W1 + (size_t)k * FIN * FH, acc1, 0);
            xprev = xn;
        }
    }
    bias_relu<<<gNH, B, 0, stream>>>(acc1, b1);

    // ---- layer 2 ----
    dense_128_6<<<gNO, B, 0, stream>>>(acc1, W2, out2, 1);
    {
        const float* xprev = acc1;
        float* bufs[2] = {xk2a, xk2b};
        for (int k = 1; k <= KH; ++k) {
            float* xn = bufs[(k - 1) & 1];
            hipMemsetAsync(xn, 0, (size_t)NN * FH * sizeof(float), stream);
            hop128<<<gE4, B, 0, stream>>>(row, col, nw, xprev, xn);
            dense_128_6<<<gNO, B, 0, stream>>>(xn, W2 + (size_t)k * FH * FO, out2, 0);
            xprev = xn;
        }
    }

    finalize<<<gNO, B, 0, stream>>>(out2, b2, out);
}

// Round 2
// 480.193 us; speedup vs baseline: 47.5625x; 47.5625x over previous
//
#include <hip/hip_runtime.h>

#define NN 50000
#define NE 800000
#define KH 4
#define FIN 6
#define FH 128
#define FO 6
#define ADIM 3
#define NN6 (NN * 6)

// ---------------- degree (weighted) + in-degree count ----------------
__global__ void deg_hist_kernel(const int* __restrict__ col, const float* __restrict__ w,
                                float* __restrict__ deg, int* __restrict__ cnt) {
    int e = blockIdx.x * blockDim.x + threadIdx.x;
    if (e >= NE) return;
    int c = col[e];
    atomicAdd(&deg[c], w[e]);
    atomicAdd(&cnt[c], 1);
}

__global__ void normw_kernel(const int* __restrict__ row, const int* __restrict__ col,
                             const float* __restrict__ w, const float* __restrict__ deg,
                             float* __restrict__ nw) {
    int e = blockIdx.x * blockDim.x + threadIdx.x;
    if (e >= NE) return;
    float dr = deg[row[e]];
    float dc = deg[col[e]];
    float ir = dr > 0.f ? rsqrtf(dr) : 0.f;
    float ic = dc > 0.f ? rsqrtf(dc) : 0.f;
    nw[e] = ir * w[e] * ic;
}

// ---------------- exclusive scan of cnt -> offs (single block) ----------------
__global__ void scan_kernel(const int* __restrict__ cnt, int* __restrict__ offs,
                            int* __restrict__ cur) {
    __shared__ int sh[1024];
    int t = threadIdx.x;
    const int C = (NN + 1023) / 1024; // 49
    int lo = t * C;
    int hi = lo + C; if (hi > NN) hi = NN; if (lo > NN) lo = NN;
    int sum = 0;
    for (int i = lo; i < hi; ++i) sum += cnt[i];
    sh[t] = sum;
    __syncthreads();
    for (int off = 1; off < 1024; off <<= 1) {
        int v = (t >= off) ? sh[t - off] : 0;
        __syncthreads();
        sh[t] += v;
        __syncthreads();
    }
    int run = sh[t] - sum; // exclusive base
    for (int i = lo; i < hi; ++i) {
        offs[i] = run;
        cur[i] = run;
        run += cnt[i];
    }
    if (t == 1023) offs[NN] = sh[1023];
}

// ---------------- scatter edges into CSR-by-destination ----------------
__global__ void scatter_kernel(const int* __restrict__ row, const int* __restrict__ col,
                               const float* __restrict__ nw, int* __restrict__ cur,
                               int* __restrict__ erow, float* __restrict__ ewt) {
    int e = blockIdx.x * blockDim.x + threadIdx.x;
    if (e >= NE) return;
    int c = col[e];
    int p = atomicAdd(&cur[c], 1);
    erow[p] = row[e];
    ewt[p] = nw[e];
}

// ---------------- 6-wide gather hop: xnext = (yadd) + A * xprev ----------------
__global__ void hop6_gather(const int* __restrict__ offs, const int* __restrict__ erow,
                            const float* __restrict__ ewt, const float* __restrict__ xprev,
                            const float* __restrict__ yadd, float* __restrict__ xnext) {
    int idx = blockIdx.x * blockDim.x + threadIdx.x;
    if (idx >= NN6) return;
    int n = idx / 6;
    int f = idx % 6;
    int s = offs[n], e = offs[n + 1];
    float acc = yadd ? yadd[idx] : 0.f;
    for (int i = s; i < e; ++i)
        acc += ewt[i] * xprev[erow[i] * 6 + f];
    xnext[idx] = acc;
}

// ---------------- layer 1 fused dense: acc1 = relu(sum_k xs[k] @ W1[k] + b1) ----------------
__global__ void dense1_kernel(const float* __restrict__ xs, const float* __restrict__ W1,
                              const float* __restrict__ b1, float* __restrict__ acc1) {
    __shared__ float sW[(KH + 1) * FIN * FH]; // 3840 floats = 15 KB
    for (int t = threadIdx.x; t < (KH + 1) * FIN * FH; t += blockDim.x) sW[t] = W1[t];
    __syncthreads();
    int n = blockIdx.x * 2 + (threadIdx.x >> 7); // 2 nodes per 256-thread block
    int f = threadIdx.x & 127;
    if (n >= NN) return;
    float s = b1[f];
#pragma unroll
    for (int k = 0; k <= KH; ++k) {
        const float* xr = xs + (size_t)k * NN6 + n * 6;
        const float* wr = sW + k * FIN * FH;
#pragma unroll
        for (int c = 0; c < FIN; ++c) s += xr[c] * wr[c * FH + f];
    }
    acc1[n * FH + f] = s > 0.f ? s : 0.f;
}

// ---------------- layer 2 projections: ys[k][n][a] = h[n] @ W2[k] (+b2 for k=0) ----------------
__global__ void proj2_kernel(const float* __restrict__ h, const float* __restrict__ W2,
                             const float* __restrict__ b2, float* __restrict__ ys) {
    __shared__ float sW[(KH + 1) * FH * FO]; // 3840 floats
    for (int t = threadIdx.x; t < (KH + 1) * FH * FO; t += blockDim.x) sW[t] = W2[t];
    __syncthreads();
    int idx = blockIdx.x * blockDim.x + threadIdx.x;
    if (idx >= (KH + 1) * NN6) return;
    int k = idx / NN6;
    int rem = idx - k * NN6;
    int n = rem / 6;
    int a = rem % 6;
    const float* hr = h + (size_t)n * FH;
    const float* wr = sW + k * FH * FO + a;
    float s = (k == 0) ? b2[a] : 0.f;
#pragma unroll 16
    for (int c = 0; c < FH; ++c) s += hr[c] * wr[c * FO];
    ys[idx] = s;
}

// ---------------- finalize: tanh / exp split ----------------
__global__ void finalize(const float* __restrict__ z, float* __restrict__ out) {
    int idx = blockIdx.x * blockDim.x + threadIdx.x;
    if (idx >= NN6) return;
    int n = idx / 6;
    int a = idx % 6;
    float v = tanhf(z[idx]);
    if (a < ADIM) out[n * ADIM + a] = v;
    else          out[NN * ADIM + n * ADIM + (a - ADIM)] = expf(2.f * v);
}

extern "C" void kernel_launch(void* const* d_in, const int* in_sizes, int n_in,
                              void* d_out, int out_size, void* d_ws, size_t ws_size,
                              hipStream_t stream) {
    const float* x  = (const float*)d_in[0];
    const int*   ei = (const int*)d_in[1];
    const float* ew = (const float*)d_in[2];
    const float* W1 = (const float*)d_in[3];
    const float* b1 = (const float*)d_in[4];
    const float* W2 = (const float*)d_in[5];
    const float* b2 = (const float*)d_in[6];
    float* out = (float*)d_out;

    const int* row = ei;
    const int* col = ei + NE;

    // workspace layout
    float* deg  = (float*)d_ws;              // NN
    int*   cnt  = (int*)(deg + NN);          // NN
    float* nw   = (float*)(cnt + NN);        // NE
    int*   offs = (int*)(nw + NE);           // NN+1
    int*   cur  = offs + NN + 1;             // NN
    int*   erow = cur + NN;                  // NE
    float* ewt  = (float*)(erow + NE);       // NE
    float* xs   = ewt + NE;                  // (KH+1)*NN6
    float* acc1 = xs + (size_t)(KH + 1) * NN6;   // NN*FH
    float* ys   = acc1 + (size_t)NN * FH;        // (KH+1)*NN6
    float* za   = ys + (size_t)(KH + 1) * NN6;   // NN6
    float* zb   = za + NN6;                      // NN6

    const int B = 256;
    const int gE  = (NE + B - 1) / B;
    const int gH  = (NN6 + B - 1) / B;
    const int gP  = ((KH + 1) * NN6 + B - 1) / B;
    const int gD1 = (NN + 1) / 2;

    // ---- norm + CSR build ----
    hipMemsetAsync(deg, 0, (size_t)2 * NN * sizeof(float), stream); // deg + cnt
    deg_hist_kernel<<<gE, B, 0, stream>>>(col, ew, deg, cnt);
    normw_kernel<<<gE, B, 0, stream>>>(row, col, ew, deg, nw);
    scan_kernel<<<1, 1024, 0, stream>>>(cnt, offs, cur);
    scatter_kernel<<<gE, B, 0, stream>>>(row, col, nw, cur, erow, ewt);

    // ---- layer 1: hops on 6-wide input features ----
    hipMemcpyAsync(xs, x, (size_t)NN6 * sizeof(float), hipMemcpyDeviceToDevice, stream);
    for (int k = 1; k <= KH; ++k) {
        hop6_gather<<<gH, B, 0, stream>>>(offs, erow, ewt,
                                          xs + (size_t)(k - 1) * NN6, nullptr,
                                          xs + (size_t)k * NN6);
    }
    dense1_kernel<<<gD1, B, 0, stream>>>(xs, W1, b1, acc1);

    // ---- layer 2: project first, then Horner on 6-wide ----
    proj2_kernel<<<gP, B, 0, stream>>>(acc1, W2, b2, ys);
    // z = y3 + A*y4 ; z = y2 + A*z ; z = y1 + A*z ; out2 = y0 + A*z
    hop6_gather<<<gH, B, 0, stream>>>(offs, erow, ewt, ys + (size_t)4 * NN6, ys + (size_t)3 * NN6, za);
    hop6_gather<<<gH, B, 0, stream>>>(offs, erow, ewt, za, ys + (size_t)2 * NN6, zb);
    hop6_gather<<<gH, B, 0, stream>>>(offs, erow, ewt, zb, ys + (size_t)1 * NN6, za);
    hop6_gather<<<gH, B, 0, stream>>>(offs, erow, ewt, za, ys, zb);

    finalize<<<gH, B, 0, stream>>>(zb, out);
}

// Round 3
// 334.731 us; speedup vs baseline: 68.2314x; 1.4346x over previous
//
#include <hip/hip_runtime.h>

#define NN 50000
#define NE 800000
#define KH 4
#define FIN 6
#define FH 128
#define FO 6
#define ADIM 3
#define NN6 (NN * 6)
#define NB 196   // (NN + 255) / 256

// ---------------- degree (weighted) + in-degree count ----------------
__global__ void deg_hist_kernel(const int* __restrict__ col, const float* __restrict__ w,
                                float* __restrict__ deg, int* __restrict__ cnt) {
    int e = blockIdx.x * blockDim.x + threadIdx.x;
    if (e >= NE) return;
    int c = col[e];
    atomicAdd(&deg[c], w[e]);
    atomicAdd(&cnt[c], 1);
}

// ---------------- two-level exclusive scan ----------------
__global__ void blocksum_kernel(const int* __restrict__ cnt, int* __restrict__ bsum) {
    __shared__ int sh[256];
    int i = blockIdx.x * 256 + threadIdx.x;
    sh[threadIdx.x] = (i < NN) ? cnt[i] : 0;
    __syncthreads();
    for (int off = 128; off > 0; off >>= 1) {
        if (threadIdx.x < off) sh[threadIdx.x] += sh[threadIdx.x + off];
        __syncthreads();
    }
    if (threadIdx.x == 0) bsum[blockIdx.x] = sh[0];
}

__global__ void bscan_kernel(const int* __restrict__ bsum, int* __restrict__ bbase,
                             int* __restrict__ offs) {
    __shared__ int sh[256];
    int t = threadIdx.x;
    int v = (t < NB) ? bsum[t] : 0;
    sh[t] = v;
    __syncthreads();
    for (int off = 1; off < 256; off <<= 1) {
        int u = (t >= off) ? sh[t - off] : 0;
        __syncthreads();
        sh[t] += u;
        __syncthreads();
    }
    if (t < NB) bbase[t] = sh[t] - v;      // exclusive base per block
    if (t == 255) offs[NN] = sh[255];      // total = NE
}

__global__ void scan_fixup_kernel(const int* __restrict__ cnt, const int* __restrict__ bbase,
                                  int* __restrict__ offs, int* __restrict__ cur) {
    __shared__ int sh[256];
    int t = threadIdx.x;
    int i = blockIdx.x * 256 + t;
    int v = (i < NN) ? cnt[i] : 0;
    sh[t] = v;
    __syncthreads();
    for (int off = 1; off < 256; off <<= 1) {
        int u = (t >= off) ? sh[t - off] : 0;
        __syncthreads();
        sh[t] += u;
        __syncthreads();
    }
    if (i < NN) {
        int o = bbase[blockIdx.x] + sh[t] - v;
        offs[i] = o;
        cur[i] = o;
    }
}

// ---------------- scatter edges into CSR-by-destination, norm fused ----------------
__global__ void scatter_kernel(const int* __restrict__ row, const int* __restrict__ col,
                               const float* __restrict__ w, const float* __restrict__ deg,
                               int* __restrict__ cur,
                               int* __restrict__ erow, float* __restrict__ ewt) {
    int e = blockIdx.x * blockDim.x + threadIdx.x;
    if (e >= NE) return;
    int r = row[e], c = col[e];
    float dr = deg[r], dc = deg[c];
    float ir = dr > 0.f ? rsqrtf(dr) : 0.f;
    float ic = dc > 0.f ? rsqrtf(dc) : 0.f;
    int p = atomicAdd(&cur[c], 1);
    erow[p] = r;
    ewt[p] = ir * w[e] * ic;
}

// ---------------- 6-wide gather hop: xnext = (yadd) + A * xprev ----------------
__global__ void hop6_gather(const int* __restrict__ offs, const int* __restrict__ erow,
                            const float* __restrict__ ewt, const float* __restrict__ xprev,
                            const float* __restrict__ yadd, float* __restrict__ xnext) {
    int idx = blockIdx.x * blockDim.x + threadIdx.x;
    if (idx >= NN6) return;
    int n = idx / 6;
    int f = idx % 6;
    int s = offs[n], e = offs[n + 1];
    float acc = yadd ? yadd[idx] : 0.f;
    for (int i = s; i < e; ++i)
        acc += ewt[i] * xprev[erow[i] * 6 + f];
    xnext[idx] = acc;
}

// ---------------- final hop fused with tanh/exp finalize ----------------
__global__ void hop6_final(const int* __restrict__ offs, const int* __restrict__ erow,
                           const float* __restrict__ ewt, const float* __restrict__ xprev,
                           const float* __restrict__ y0, float* __restrict__ out) {
    int idx = blockIdx.x * blockDim.x + threadIdx.x;
    if (idx >= NN6) return;
    int n = idx / 6;
    int f = idx % 6;
    int s = offs[n], e = offs[n + 1];
    float acc = y0[idx];
    for (int i = s; i < e; ++i)
        acc += ewt[i] * xprev[erow[i] * 6 + f];
    float v = tanhf(acc);
    if (f < ADIM) out[n * ADIM + f] = v;
    else          out[NN * ADIM + n * ADIM + (f - ADIM)] = expf(2.f * v);
}

// ---------------- layer 1 fused dense: acc1 = relu(x@W1[0] + sum_k xs[k-1]@W1[k] + b1) ----------------
__global__ void dense1_kernel(const float* __restrict__ x, const float* __restrict__ xs,
                              const float* __restrict__ W1, const float* __restrict__ b1,
                              float* __restrict__ acc1) {
    __shared__ float sW[(KH + 1) * FIN * FH]; // 3840 floats = 15 KB
    for (int t = threadIdx.x; t < (KH + 1) * FIN * FH; t += blockDim.x) sW[t] = W1[t];
    __syncthreads();
    int n = blockIdx.x * 2 + (threadIdx.x >> 7);
    int f = threadIdx.x & 127;
    if (n >= NN) return;
    float s = b1[f];
    {
        const float* xr = x + n * FIN;
#pragma unroll
        for (int c = 0; c < FIN; ++c) s += xr[c] * sW[c * FH + f];
    }
#pragma unroll
    for (int k = 1; k <= KH; ++k) {
        const float* xr = xs + (size_t)(k - 1) * NN6 + n * 6;
        const float* wr = sW + k * FIN * FH;
#pragma unroll
        for (int c = 0; c < FIN; ++c) s += xr[c] * wr[c * FH + f];
    }
    acc1[n * FH + f] = s > 0.f ? s : 0.f;
}

// ---------------- layer 2 projections: ys[k][n][a] = h[n] @ W2[k] (+b2 for k=0) ----------------
__global__ void proj2_kernel(const float* __restrict__ h, const float* __restrict__ W2,
                             const float* __restrict__ b2, float* __restrict__ ys) {
    __shared__ float sW[(KH + 1) * FH * FO]; // 3840 floats
    for (int t = threadIdx.x; t < (KH + 1) * FH * FO; t += blockDim.x) sW[t] = W2[t];
    __syncthreads();
    int idx = blockIdx.x * blockDim.x + threadIdx.x;
    if (idx >= NN6) return;
    int n = idx / 6;
    int a = idx % 6;
    const float4* hr = (const float4*)(h + (size_t)n * FH);
    float s0 = b2[a], s1 = 0.f, s2 = 0.f, s3 = 0.f, s4 = 0.f;
#pragma unroll 8
    for (int c4 = 0; c4 < FH / 4; ++c4) {
        float4 hv = hr[c4];
        const float* w0 = sW + (c4 * 4) * FO + a;
#pragma unroll
        for (int j = 0; j < 4; ++j) {
            float hj = j == 0 ? hv.x : j == 1 ? hv.y : j == 2 ? hv.z : hv.w;
            s0 += hj * w0[j * FO];
            s1 += hj * w0[1 * FH * FO + j * FO];
            s2 += hj * w0[2 * FH * FO + j * FO];
            s3 += hj * w0[3 * FH * FO + j * FO];
            s4 += hj * w0[4 * FH * FO + j * FO];
        }
    }
    ys[idx] = s0;
    ys[1 * NN6 + idx] = s1;
    ys[2 * NN6 + idx] = s2;
    ys[3 * NN6 + idx] = s3;
    ys[4 * NN6 + idx] = s4;
}

extern "C" void kernel_launch(void* const* d_in, const int* in_sizes, int n_in,
                              void* d_out, int out_size, void* d_ws, size_t ws_size,
                              hipStream_t stream) {
    const float* x  = (const float*)d_in[0];
    const int*   ei = (const int*)d_in[1];
    const float* ew = (const float*)d_in[2];
    const float* W1 = (const float*)d_in[3];
    const float* b1 = (const float*)d_in[4];
    const float* W2 = (const float*)d_in[5];
    const float* b2 = (const float*)d_in[6];
    float* out = (float*)d_out;

    const int* row = ei;
    const int* col = ei + NE;

    // workspace layout
    float* deg  = (float*)d_ws;              // NN
    int*   cnt  = (int*)(deg + NN);          // NN
    int*   bsum = cnt + NN;                  // NB
    int*   bbase= bsum + NB;                 // NB
    int*   offs = bbase + NB;                // NN+1
    int*   cur  = offs + NN + 1;             // NN
    int*   erow = cur + NN;                  // NE
    float* ewt  = (float*)(erow + NE);       // NE
    float* xs   = ewt + NE;                  // KH*NN6  (hop outputs, planes 1..4)
    float* acc1 = xs + (size_t)KH * NN6;     // NN*FH
    float* ys   = acc1 + (size_t)NN * FH;    // (KH+1)*NN6
    float* za   = ys + (size_t)(KH + 1) * NN6; // NN6
    float* zb   = za + NN6;                  // NN6

    const int B = 256;
    const int gE = (NE + B - 1) / B;
    const int gH = (NN6 + B - 1) / B;
    const int gD1 = (NN + 1) / 2;

    // ---- norm + CSR build ----
    hipMemsetAsync(deg, 0, (size_t)2 * NN * sizeof(float), stream); // deg + cnt
    deg_hist_kernel<<<gE, B, 0, stream>>>(col, ew, deg, cnt);
    blocksum_kernel<<<NB, 256, 0, stream>>>(cnt, bsum);
    bscan_kernel<<<1, 256, 0, stream>>>(bsum, bbase, offs);
    scan_fixup_kernel<<<NB, 256, 0, stream>>>(cnt, bbase, offs, cur);
    scatter_kernel<<<gE, B, 0, stream>>>(row, col, ew, deg, cur, erow, ewt);

    // ---- layer 1: hops on 6-wide input features ----
    hop6_gather<<<gH, B, 0, stream>>>(offs, erow, ewt, x, nullptr, xs);
    for (int k = 2; k <= KH; ++k)
        hop6_gather<<<gH, B, 0, stream>>>(offs, erow, ewt,
                                          xs + (size_t)(k - 2) * NN6, nullptr,
                                          xs + (size_t)(k - 1) * NN6);
    dense1_kernel<<<gD1, B, 0, stream>>>(x, xs, W1, b1, acc1);

    // ---- layer 2: project first, then Horner on 6-wide ----
    proj2_kernel<<<gH, B, 0, stream>>>(acc1, W2, b2, ys);
    hop6_gather<<<gH, B, 0, stream>>>(offs, erow, ewt, ys + (size_t)4 * NN6, ys + (size_t)3 * NN6, za);
    hop6_gather<<<gH, B, 0, stream>>>(offs, erow, ewt, za, ys + (size_t)2 * NN6, zb);
    hop6_gather<<<gH, B, 0, stream>>>(offs, erow, ewt, zb, ys + (size_t)1 * NN6, za);
    hop6_final<<<gH, B, 0, stream>>>(offs, erow, ewt, za, ys, out);
}

// Round 4
// 232.007 us; speedup vs baseline: 98.4415x; 1.4428x over previous
//
#include <hip/hip_runtime.h>

#define NN 50000
#define NE 800000
#define KH 4
#define FIN 6
#define FH 128
#define FO 6
#define ADIM 3
#define NN6 (NN * 6)
#define NB 196   // (NN + 255) / 256

typedef unsigned long long ull;
#define CNT_SHIFT 56
#define SUM_MASK ((1ULL << CNT_SHIFT) - 1)

struct __align__(8) Edge { int r; float w; };

// ---------------- packed degree histogram: one 64-bit atomic per edge ----------------
// high 8 bits: in-degree count; low 56 bits: fixed-point (2^-40) weighted degree sum
__global__ void deg_hist_kernel(const int* __restrict__ col, const float* __restrict__ w,
                                ull* __restrict__ dh) {
    int e = blockIdx.x * blockDim.x + threadIdx.x;
    if (e >= NE) return;
    ull p = (1ULL << CNT_SHIFT) | (ull)((double)w[e] * 0x1p40);
    atomicAdd(&dh[col[e]], p);
}

// ---------------- two-level exclusive scan over packed counts ----------------
__global__ void blocksum_kernel(const ull* __restrict__ dh, int* __restrict__ bsum) {
    __shared__ int sh[256];
    int i = blockIdx.x * 256 + threadIdx.x;
    sh[threadIdx.x] = (i < NN) ? (int)(dh[i] >> CNT_SHIFT) : 0;
    __syncthreads();
    for (int off = 128; off > 0; off >>= 1) {
        if (threadIdx.x < off) sh[threadIdx.x] += sh[threadIdx.x + off];
        __syncthreads();
    }
    if (threadIdx.x == 0) bsum[blockIdx.x] = sh[0];
}

__global__ void bscan_kernel(const int* __restrict__ bsum, int* __restrict__ bbase,
                             int* __restrict__ offs) {
    __shared__ int sh[256];
    int t = threadIdx.x;
    int v = (t < NB) ? bsum[t] : 0;
    sh[t] = v;
    __syncthreads();
    for (int off = 1; off < 256; off <<= 1) {
        int u = (t >= off) ? sh[t - off] : 0;
        __syncthreads();
        sh[t] += u;
        __syncthreads();
    }
    if (t < NB) bbase[t] = sh[t] - v;
    if (t == 255) offs[NN] = sh[255];
}

__global__ void scan_fixup_kernel(const ull* __restrict__ dh, const int* __restrict__ bbase,
                                  int* __restrict__ offs, int* __restrict__ cur) {
    __shared__ int sh[256];
    int t = threadIdx.x;
    int i = blockIdx.x * 256 + t;
    int v = (i < NN) ? (int)(dh[i] >> CNT_SHIFT) : 0;
    sh[t] = v;
    __syncthreads();
    for (int off = 1; off < 256; off <<= 1) {
        int u = (t >= off) ? sh[t - off] : 0;
        __syncthreads();
        sh[t] += u;
        __syncthreads();
    }
    if (i < NN) {
        int o = bbase[blockIdx.x] + sh[t] - v;
        offs[i] = o;
        cur[i] = o;
    }
}

// ---------------- scatter into CSR-by-destination, norm fused, packed 8B record ----------------
__global__ void scatter_kernel(const int* __restrict__ row, const int* __restrict__ col,
                               const float* __restrict__ w, const ull* __restrict__ dh,
                               int* __restrict__ cur, Edge* __restrict__ edges) {
    int e = blockIdx.x * blockDim.x + threadIdx.x;
    if (e >= NE) return;
    int r = row[e], c = col[e];
    float dr = (float)((double)(dh[r] & SUM_MASK) * 0x1p-40);
    float dc = (float)((double)(dh[c] & SUM_MASK) * 0x1p-40);
    float ir = dr > 0.f ? rsqrtf(dr) : 0.f;
    float ic = dc > 0.f ? rsqrtf(dc) : 0.f;
    int p = atomicAdd(&cur[c], 1);
    Edge ed; ed.r = r; ed.w = ir * w[e] * ic;
    edges[p] = ed;
}

// ---------------- hop: 8 lanes per node, shfl-reduce; xnext = yadd + A*xprev ----------------
__global__ void hop8(const int* __restrict__ offs, const Edge* __restrict__ edges,
                     const float* __restrict__ xprev, const float* __restrict__ yadd,
                     float* __restrict__ xnext) {
    int t = blockIdx.x * blockDim.x + threadIdx.x;
    int n = t >> 3, j = t & 7;
    if (n >= NN) return;
    int s = offs[n], e = offs[n + 1];
    float a0 = 0.f, a1 = 0.f, a2 = 0.f, a3 = 0.f, a4 = 0.f, a5 = 0.f;
    for (int i = s + j; i < e; i += 8) {
        Edge ed = edges[i];
        const float* xr = xprev + (size_t)ed.r * 6;
        a0 += ed.w * xr[0]; a1 += ed.w * xr[1]; a2 += ed.w * xr[2];
        a3 += ed.w * xr[3]; a4 += ed.w * xr[4]; a5 += ed.w * xr[5];
    }
#pragma unroll
    for (int d = 1; d < 8; d <<= 1) {
        a0 += __shfl_xor(a0, d); a1 += __shfl_xor(a1, d); a2 += __shfl_xor(a2, d);
        a3 += __shfl_xor(a3, d); a4 += __shfl_xor(a4, d); a5 += __shfl_xor(a5, d);
    }
    if (j < 6) {
        float v = j == 0 ? a0 : j == 1 ? a1 : j == 2 ? a2 : j == 3 ? a3 : j == 4 ? a4 : a5;
        if (yadd) v += yadd[n * 6 + j];
        xnext[n * 6 + j] = v;
    }
}

// ---------------- final hop fused with tanh/exp finalize ----------------
__global__ void hop8_final(const int* __restrict__ offs, const Edge* __restrict__ edges,
                           const float* __restrict__ xprev, const float* __restrict__ y0,
                           float* __restrict__ out) {
    int t = blockIdx.x * blockDim.x + threadIdx.x;
    int n = t >> 3, j = t & 7;
    if (n >= NN) return;
    int s = offs[n], e = offs[n + 1];
    float a0 = 0.f, a1 = 0.f, a2 = 0.f, a3 = 0.f, a4 = 0.f, a5 = 0.f;
    for (int i = s + j; i < e; i += 8) {
        Edge ed = edges[i];
        const float* xr = xprev + (size_t)ed.r * 6;
        a0 += ed.w * xr[0]; a1 += ed.w * xr[1]; a2 += ed.w * xr[2];
        a3 += ed.w * xr[3]; a4 += ed.w * xr[4]; a5 += ed.w * xr[5];
    }
#pragma unroll
    for (int d = 1; d < 8; d <<= 1) {
        a0 += __shfl_xor(a0, d); a1 += __shfl_xor(a1, d); a2 += __shfl_xor(a2, d);
        a3 += __shfl_xor(a3, d); a4 += __shfl_xor(a4, d); a5 += __shfl_xor(a5, d);
    }
    if (j < 6) {
        float v = j == 0 ? a0 : j == 1 ? a1 : j == 2 ? a2 : j == 3 ? a3 : j == 4 ? a4 : a5;
        v += y0[n * 6 + j];
        float tv = tanhf(v);
        if (j < ADIM) out[n * ADIM + j] = tv;
        else          out[NN * ADIM + n * ADIM + (j - ADIM)] = expf(2.f * tv);
    }
}

// ---------------- layer 1 fused dense (grid-stride, weights loaded once/block) ----------------
__global__ void dense1_kernel(const float* __restrict__ x, const float* __restrict__ xs,
                              const float* __restrict__ W1, const float* __restrict__ b1,
                              float* __restrict__ acc1) {
    __shared__ float sW[(KH + 1) * FIN * FH]; // 3840 floats = 15 KB
    for (int t = threadIdx.x; t < (KH + 1) * FIN * FH; t += blockDim.x) sW[t] = W1[t];
    __syncthreads();
    int f = threadIdx.x & 127;
    int half = threadIdx.x >> 7;
    float bf = b1[f];
    for (int n = blockIdx.x * 2 + half; n < NN; n += gridDim.x * 2) {
        float s = bf;
        const float* xr = x + n * FIN;
#pragma unroll
        for (int c = 0; c < FIN; ++c) s += xr[c] * sW[c * FH + f];
#pragma unroll
        for (int k = 1; k <= KH; ++k) {
            const float* xk = xs + (size_t)(k - 1) * NN6 + n * 6;
            const float* wr = sW + k * FIN * FH;
#pragma unroll
            for (int c = 0; c < FIN; ++c) s += xk[c] * wr[c * FH + f];
        }
        acc1[(size_t)n * FH + f] = s > 0.f ? s : 0.f;
    }
}

// ---------------- layer 2 projections (grid-stride): ys[k][n][a] = h[n]@W2[k] (+b2 k=0) ----------------
__global__ void proj2_kernel(const float* __restrict__ h, const float* __restrict__ W2,
                             const float* __restrict__ b2, float* __restrict__ ys) {
    __shared__ float sW[(KH + 1) * FH * FO]; // 3840 floats
    for (int t = threadIdx.x; t < (KH + 1) * FH * FO; t += blockDim.x) sW[t] = W2[t];
    __syncthreads();
    for (int idx = blockIdx.x * blockDim.x + threadIdx.x; idx < NN6;
         idx += gridDim.x * blockDim.x) {
        int n = idx / 6;
        int a = idx % 6;
        const float4* hr = (const float4*)(h + (size_t)n * FH);
        float s0 = b2[a], s1 = 0.f, s2 = 0.f, s3 = 0.f, s4 = 0.f;
#pragma unroll 8
        for (int c4 = 0; c4 < FH / 4; ++c4) {
            float4 hv = hr[c4];
            const float* w0 = sW + (c4 * 4) * FO + a;
#pragma unroll
            for (int j = 0; j < 4; ++j) {
                float hj = j == 0 ? hv.x : j == 1 ? hv.y : j == 2 ? hv.z : hv.w;
                s0 += hj * w0[j * FO];
                s1 += hj * w0[1 * FH * FO + j * FO];
                s2 += hj * w0[2 * FH * FO + j * FO];
                s3 += hj * w0[3 * FH * FO + j * FO];
                s4 += hj * w0[4 * FH * FO + j * FO];
            }
        }
        ys[idx] = s0;
        ys[1 * NN6 + idx] = s1;
        ys[2 * NN6 + idx] = s2;
        ys[3 * NN6 + idx] = s3;
        ys[4 * NN6 + idx] = s4;
    }
}

extern "C" void kernel_launch(void* const* d_in, const int* in_sizes, int n_in,
                              void* d_out, int out_size, void* d_ws, size_t ws_size,
                              hipStream_t stream) {
    const float* x  = (const float*)d_in[0];
    const int*   ei = (const int*)d_in[1];
    const float* ew = (const float*)d_in[2];
    const float* W1 = (const float*)d_in[3];
    const float* b1 = (const float*)d_in[4];
    const float* W2 = (const float*)d_in[5];
    const float* b2 = (const float*)d_in[6];
    float* out = (float*)d_out;

    const int* row = ei;
    const int* col = ei + NE;

    // workspace layout (8B-aligned things first)
    ull*   dh    = (ull*)d_ws;                 // NN
    Edge*  edges = (Edge*)(dh + NN);           // NE
    int*   bsum  = (int*)(edges + NE);         // NB
    int*   bbase = bsum + NB;                  // NB
    int*   offs  = bbase + NB;                 // NN+1
    int*   cur   = offs + NN + 1;              // NN
    float* xs    = (float*)(cur + NN);         // KH*NN6
    float* acc1  = xs + (size_t)KH * NN6;      // NN*FH
    float* ys    = acc1 + (size_t)NN * FH;     // (KH+1)*NN6
    float* za    = ys + (size_t)(KH + 1) * NN6; // NN6
    float* zb    = za + NN6;                   // NN6

    const int B = 256;
    const int gE = (NE + B - 1) / B;
    const int gHop = (NN * 8 + B - 1) / B;

    // ---- norm + CSR build ----
    hipMemsetAsync(dh, 0, (size_t)NN * sizeof(ull), stream);
    deg_hist_kernel<<<gE, B, 0, stream>>>(col, ew, dh);
    blocksum_kernel<<<NB, 256, 0, stream>>>(dh, bsum);
    bscan_kernel<<<1, 256, 0, stream>>>(bsum, bbase, offs);
    scan_fixup_kernel<<<NB, 256, 0, stream>>>(dh, bbase, offs, cur);
    scatter_kernel<<<gE, B, 0, stream>>>(row, col, ew, dh, cur, edges);

    // ---- layer 1: hops on 6-wide input features ----
    hop8<<<gHop, B, 0, stream>>>(offs, edges, x, nullptr, xs);
    for (int k = 2; k <= KH; ++k)
        hop8<<<gHop, B, 0, stream>>>(offs, edges,
                                     xs + (size_t)(k - 2) * NN6, nullptr,
                                     xs + (size_t)(k - 1) * NN6);
    dense1_kernel<<<512, 256, 0, stream>>>(x, xs, W1, b1, acc1);

    // ---- layer 2: project first, then Horner on 6-wide ----
    proj2_kernel<<<512, B, 0, stream>>>(acc1, W2, b2, ys);
    hop8<<<gHop, B, 0, stream>>>(offs, edges, ys + (size_t)4 * NN6, ys + (size_t)3 * NN6, za);
    hop8<<<gHop, B, 0, stream>>>(offs, edges, za, ys + (size_t)2 * NN6, zb);
    hop8<<<gHop, B, 0, stream>>>(offs, edges, zb, ys + (size_t)1 * NN6, za);
    hop8_final<<<gHop, B, 0, stream>>>(offs, edges, za, ys, out);
}

// Round 5
// 194.030 us; speedup vs baseline: 117.7091x; 1.1957x over previous
//
#include <hip/hip_runtime.h>

#define NN 50000
#define NE 800000
#define KH 4
#define FIN 6
#define FH 128
#define FO 6
#define ADIM 3
#define NN6 (NN * 6)
#define NBKT 196        // ceil(NN / 256) buckets of 256 node ids
#define EPB 2048        // edges per partition block
#define NPB 391         // ceil(NE / EPB)
#define CAP 5120        // LDS staging capacity per bucket (mean 4082, ~16 sigma headroom)
#define ROWMASK 0xFFFFFu

typedef unsigned int u32;

struct __align__(8) Edge { u32 r; float w; };

// ---------------- K1: bucket histogram (col >> 8) ----------------
__global__ void bucket_hist(const int* __restrict__ col, u32* __restrict__ ghist) {
    __shared__ u32 h[NBKT];
    for (int t = threadIdx.x; t < NBKT; t += 256) h[t] = 0;
    __syncthreads();
    int base = blockIdx.x * EPB;
#pragma unroll
    for (int i = 0; i < EPB / 256; ++i) {
        int e = base + i * 256 + threadIdx.x;
        if (e < NE) atomicAdd(&h[((u32)col[e]) >> 8], 1u);
    }
    __syncthreads();
    for (int t = threadIdx.x; t < NBKT; t += 256)
        if (h[t]) atomicAdd(&ghist[t], h[t]);
}

// ---------------- K2: scan bucket counts -> bases/cursors ----------------
__global__ void bucket_scan(const u32* __restrict__ ghist, u32* __restrict__ bbase,
                            u32* __restrict__ bcur, int* __restrict__ offs) {
    __shared__ u32 sh[256];
    int t = threadIdx.x;
    u32 v = (t < NBKT) ? ghist[t] : 0;
    sh[t] = v;
    __syncthreads();
    for (int off = 1; off < 256; off <<= 1) {
        u32 u = (t >= off) ? sh[t - off] : 0;
        __syncthreads();
        sh[t] += u;
        __syncthreads();
    }
    if (t < NBKT) { bbase[t] = sh[t] - v; bcur[t] = sh[t] - v; }
    if (t == NBKT - 1) bbase[NBKT] = sh[t];
    if (t == 0) offs[NN] = NE;
}

// ---------------- K3: partition edges into bucket-grouped etmp (LDS-staged) ----------------
__global__ __launch_bounds__(256) void partition_kernel(
        const int* __restrict__ row, const int* __restrict__ col,
        const float* __restrict__ w, u32* __restrict__ bcur,
        Edge* __restrict__ etmp) {
    __shared__ u32 hcnt[NBKT];
    __shared__ u32 hloc[NBKT];
    __shared__ u32 hglb[NBKT];
    __shared__ u32 smeta[EPB];
    __shared__ float swt[EPB];
    __shared__ u32 sgid[EPB];
    __shared__ u32 sc[256];
    for (int t = threadIdx.x; t < NBKT; t += 256) hcnt[t] = 0;
    __syncthreads();
    int base = blockIdx.x * EPB;
    u32 m_[8]; float w_[8]; u32 b_[8]; u32 rk_[8]; int v_[8];
#pragma unroll
    for (int i = 0; i < 8; ++i) {
        int e = base + i * 256 + threadIdx.x;
        v_[i] = e < NE;
        if (v_[i]) {
            u32 c = (u32)col[e];
            u32 r = (u32)row[e];
            b_[i] = c >> 8;
            m_[i] = ((c & 255u) << 20) | r;
            w_[i] = w[e];
            rk_[i] = atomicAdd(&hcnt[b_[i]], 1u);
        }
    }
    __syncthreads();
    {   // exclusive scan of hcnt -> hloc
        int t = threadIdx.x;
        u32 v = (t < NBKT) ? hcnt[t] : 0;
        sc[t] = v;
        __syncthreads();
        for (int off = 1; off < 256; off <<= 1) {
            u32 u = (t >= off) ? sc[t - off] : 0;
            __syncthreads();
            sc[t] += u;
            __syncthreads();
        }
        if (t < NBKT) hloc[t] = sc[t] - v;
    }
    __syncthreads();
    for (int t = threadIdx.x; t < NBKT; t += 256)
        if (hcnt[t]) hglb[t] = atomicAdd(&bcur[t], hcnt[t]);
    __syncthreads();
#pragma unroll
    for (int i = 0; i < 8; ++i) if (v_[i]) {
        u32 slot = hloc[b_[i]] + rk_[i];
        smeta[slot] = m_[i];
        swt[slot] = w_[i];
        sgid[slot] = hglb[b_[i]] + rk_[i];
    }
    __syncthreads();
    int tot = NE - base; if (tot > EPB) tot = EPB;
    for (int s = threadIdx.x; s < tot; s += 256) {
        Edge ed; ed.r = smeta[s]; ed.w = swt[s];
        etmp[sgid[s]] = ed;   // bucket runs -> mostly lane-consecutive
    }
}

// ---------------- K4: per-bucket CSR build + deg/dinv + offs (no global atomics) ----------------
__global__ __launch_bounds__(256) void bucket_csr(
        const u32* __restrict__ bbase, const Edge* __restrict__ etmp,
        Edge* __restrict__ edges, int* __restrict__ offs,
        float* __restrict__ dinv) {
    int b = blockIdx.x;
    int t = threadIdx.x;
    u32 s = bbase[b], e = bbase[b + 1];
    int cnt = (int)(e - s);
    int node0 = b << 8;
    int nloc = NN - node0; if (nloc > 256) nloc = 256;
    __shared__ u32 ncnt[256];
    __shared__ float nsum[256];
    __shared__ u32 ncur[256];
    __shared__ u32 sc[256];
    __shared__ Edge stage[CAP];   // 40 KB
    ncnt[t] = 0; nsum[t] = 0.f;
    __syncthreads();
    for (int i = t; i < cnt; i += 256) {
        Edge ed = etmp[s + i];
        u32 cl = ed.r >> 20;
        atomicAdd(&ncnt[cl], 1u);
        atomicAdd(&nsum[cl], ed.w);
    }
    __syncthreads();
    u32 v = ncnt[t];
    sc[t] = v;
    __syncthreads();
    for (int off = 1; off < 256; off <<= 1) {
        u32 u = (t >= off) ? sc[t - off] : 0;
        __syncthreads();
        sc[t] += u;
        __syncthreads();
    }
    u32 excl = sc[t] - v;
    ncur[t] = excl;
    if (t < nloc) {
        offs[node0 + t] = (int)(s + excl);
        float d = nsum[t];
        dinv[node0 + t] = d > 0.f ? rsqrtf(d) : 0.f;
    }
    __syncthreads();
    for (int i = t; i < cnt; i += 256) {
        Edge ed = etmp[s + i];
        u32 cl = ed.r >> 20;
        u32 slot = atomicAdd(&ncur[cl], 1u);
        Edge ce; ce.r = ed.r & ROWMASK; ce.w = ed.w;
        if (slot < CAP) stage[slot] = ce;
        else edges[s + slot] = ce;           // overflow fallback (statistically never)
    }
    __syncthreads();
    int lim = cnt < CAP ? cnt : CAP;
    for (int i = t; i < lim; i += 256) edges[s + i] = stage[i];
}

// ---------------- K5: normalize edge weights in place ----------------
__global__ void norm_kernel(const int* __restrict__ offs, const float* __restrict__ dinv,
                            Edge* __restrict__ edges) {
    int tt = blockIdx.x * blockDim.x + threadIdx.x;
    int n = tt >> 3, j = tt & 7;
    if (n >= NN) return;
    int s = offs[n], e = offs[n + 1];
    float dn = dinv[n];
    for (int i = s + j; i < e; i += 8) {
        Edge ed = edges[i];
        ed.w = ed.w * dn * dinv[ed.r];
        edges[i] = ed;
    }
}

// ---------------- hop: 8 lanes per node, shfl-reduce; xnext = yadd + A*xprev ----------------
__global__ void hop8(const int* __restrict__ offs, const Edge* __restrict__ edges,
                     const float* __restrict__ xprev, const float* __restrict__ yadd,
                     float* __restrict__ xnext) {
    int t = blockIdx.x * blockDim.x + threadIdx.x;
    int n = t >> 3, j = t & 7;
    if (n >= NN) return;
    int s = offs[n], e = offs[n + 1];
    float a0 = 0.f, a1 = 0.f, a2 = 0.f, a3 = 0.f, a4 = 0.f, a5 = 0.f;
    for (int i = s + j; i < e; i += 8) {
        Edge ed = edges[i];
        const float* xr = xprev + (size_t)ed.r * 6;
        a0 += ed.w * xr[0]; a1 += ed.w * xr[1]; a2 += ed.w * xr[2];
        a3 += ed.w * xr[3]; a4 += ed.w * xr[4]; a5 += ed.w * xr[5];
    }
#pragma unroll
    for (int d = 1; d < 8; d <<= 1) {
        a0 += __shfl_xor(a0, d); a1 += __shfl_xor(a1, d); a2 += __shfl_xor(a2, d);
        a3 += __shfl_xor(a3, d); a4 += __shfl_xor(a4, d); a5 += __shfl_xor(a5, d);
    }
    if (j < 6) {
        float v = j == 0 ? a0 : j == 1 ? a1 : j == 2 ? a2 : j == 3 ? a3 : j == 4 ? a4 : a5;
        if (yadd) v += yadd[n * 6 + j];
        xnext[n * 6 + j] = v;
    }
}

// ---------------- final hop fused with tanh/exp finalize ----------------
__global__ void hop8_final(const int* __restrict__ offs, const Edge* __restrict__ edges,
                           const float* __restrict__ xprev, const float* __restrict__ y0,
                           float* __restrict__ out) {
    int t = blockIdx.x * blockDim.x + threadIdx.x;
    int n = t >> 3, j = t & 7;
    if (n >= NN) return;
    int s = offs[n], e = offs[n + 1];
    float a0 = 0.f, a1 = 0.f, a2 = 0.f, a3 = 0.f, a4 = 0.f, a5 = 0.f;
    for (int i = s + j; i < e; i += 8) {
        Edge ed = edges[i];
        const float* xr = xprev + (size_t)ed.r * 6;
        a0 += ed.w * xr[0]; a1 += ed.w * xr[1]; a2 += ed.w * xr[2];
        a3 += ed.w * xr[3]; a4 += ed.w * xr[4]; a5 += ed.w * xr[5];
    }
#pragma unroll
    for (int d = 1; d < 8; d <<= 1) {
        a0 += __shfl_xor(a0, d); a1 += __shfl_xor(a1, d); a2 += __shfl_xor(a2, d);
        a3 += __shfl_xor(a3, d); a4 += __shfl_xor(a4, d); a5 += __shfl_xor(a5, d);
    }
    if (j < 6) {
        float v = j == 0 ? a0 : j == 1 ? a1 : j == 2 ? a2 : j == 3 ? a3 : j == 4 ? a4 : a5;
        v += y0[n * 6 + j];
        float tv = tanhf(v);
        if (j < ADIM) out[n * ADIM + j] = tv;
        else          out[NN * ADIM + n * ADIM + (j - ADIM)] = expf(2.f * tv);
    }
}

// ---------------- layer 1 fused dense (grid-stride) ----------------
__global__ void dense1_kernel(const float* __restrict__ x, const float* __restrict__ xs,
                              const float* __restrict__ W1, const float* __restrict__ b1,
                              float* __restrict__ acc1) {
    __shared__ float sW[(KH + 1) * FIN * FH];
    for (int t = threadIdx.x; t < (KH + 1) * FIN * FH; t += blockDim.x) sW[t] = W1[t];
    __syncthreads();
    int f = threadIdx.x & 127;
    int half = threadIdx.x >> 7;
    float bf = b1[f];
    for (int n = blockIdx.x * 2 + half; n < NN; n += gridDim.x * 2) {
        float s = bf;
        const float* xr = x + n * FIN;
#pragma unroll
        for (int c = 0; c < FIN; ++c) s += xr[c] * sW[c * FH + f];
#pragma unroll
        for (int k = 1; k <= KH; ++k) {
            const float* xk = xs + (size_t)(k - 1) * NN6 + n * 6;
            const float* wr = sW + k * FIN * FH;
#pragma unroll
            for (int c = 0; c < FIN; ++c) s += xk[c] * wr[c * FH + f];
        }
        acc1[(size_t)n * FH + f] = s > 0.f ? s : 0.f;
    }
}

// ---------------- layer 2 projections (grid-stride) ----------------
__global__ void proj2_kernel(const float* __restrict__ h, const float* __restrict__ W2,
                             const float* __restrict__ b2, float* __restrict__ ys) {
    __shared__ float sW[(KH + 1) * FH * FO];
    for (int t = threadIdx.x; t < (KH + 1) * FH * FO; t += blockDim.x) sW[t] = W2[t];
    __syncthreads();
    for (int idx = blockIdx.x * blockDim.x + threadIdx.x; idx < NN6;
         idx += gridDim.x * blockDim.x) {
        int n = idx / 6;
        int a = idx % 6;
        const float4* hr = (const float4*)(h + (size_t)n * FH);
        float s0 = b2[a], s1 = 0.f, s2 = 0.f, s3 = 0.f, s4 = 0.f;
#pragma unroll 8
        for (int c4 = 0; c4 < FH / 4; ++c4) {
            float4 hv = hr[c4];
            const float* w0 = sW + (c4 * 4) * FO + a;
#pragma unroll
            for (int j = 0; j < 4; ++j) {
                float hj = j == 0 ? hv.x : j == 1 ? hv.y : j == 2 ? hv.z : hv.w;
                s0 += hj * w0[j * FO];
                s1 += hj * w0[1 * FH * FO + j * FO];
                s2 += hj * w0[2 * FH * FO + j * FO];
                s3 += hj * w0[3 * FH * FO + j * FO];
                s4 += hj * w0[4 * FH * FO + j * FO];
            }
        }
        ys[idx] = s0;
        ys[1 * NN6 + idx] = s1;
        ys[2 * NN6 + idx] = s2;
        ys[3 * NN6 + idx] = s3;
        ys[4 * NN6 + idx] = s4;
    }
}

extern "C" void kernel_launch(void* const* d_in, const int* in_sizes, int n_in,
                              void* d_out, int out_size, void* d_ws, size_t ws_size,
                              hipStream_t stream) {
    const float* x  = (const float*)d_in[0];
    const int*   ei = (const int*)d_in[1];
    const float* ew = (const float*)d_in[2];
    const float* W1 = (const float*)d_in[3];
    const float* b1 = (const float*)d_in[4];
    const float* W2 = (const float*)d_in[5];
    const float* b2 = (const float*)d_in[6];
    float* out = (float*)d_out;

    const int* row = ei;
    const int* col = ei + NE;

    // workspace layout (8B-aligned Edge arrays first)
    Edge*  etmp  = (Edge*)d_ws;                 // NE
    Edge*  edges = etmp + NE;                   // NE
    u32*   ghist = (u32*)(edges + NE);          // NBKT
    u32*   bbase = ghist + NBKT;                // NBKT+1
    u32*   bcur  = bbase + NBKT + 1;            // NBKT
    int*   offs  = (int*)(bcur + NBKT);         // NN+1
    float* dinv  = (float*)(offs + NN + 1);     // NN
    float* xs    = dinv + NN;                   // KH*NN6
    float* acc1  = xs + (size_t)KH * NN6;       // NN*FH
    float* ys    = acc1 + (size_t)NN * FH;      // (KH+1)*NN6
    float* za    = ys + (size_t)(KH + 1) * NN6; // NN6
    float* zb    = za + NN6;                    // NN6

    const int B = 256;
    const int gHop = (NN * 8 + B - 1) / B;

    // ---- CSR build (bucketed counting sort, no HBM-side atomic storms) ----
    hipMemsetAsync(ghist, 0, NBKT * sizeof(u32), stream);
    bucket_hist<<<NPB, B, 0, stream>>>(col, ghist);
    bucket_scan<<<1, B, 0, stream>>>(ghist, bbase, bcur, offs);
    partition_kernel<<<NPB, B, 0, stream>>>(row, col, ew, bcur, etmp);
    bucket_csr<<<NBKT, B, 0, stream>>>(bbase, etmp, edges, offs, dinv);
    norm_kernel<<<gHop, B, 0, stream>>>(offs, dinv, edges);

    // ---- layer 1: hops on 6-wide input features ----
    hop8<<<gHop, B, 0, stream>>>(offs, edges, x, nullptr, xs);
    for (int k = 2; k <= KH; ++k)
        hop8<<<gHop, B, 0, stream>>>(offs, edges,
                                     xs + (size_t)(k - 2) * NN6, nullptr,
                                     xs + (size_t)(k - 1) * NN6);
    dense1_kernel<<<512, B, 0, stream>>>(x, xs, W1, b1, acc1);

    // ---- layer 2: project first, then Horner on 6-wide ----
    proj2_kernel<<<512, B, 0, stream>>>(acc1, W2, b2, ys);
    hop8<<<gHop, B, 0, stream>>>(offs, edges, ys + (size_t)4 * NN6, ys + (size_t)3 * NN6, za);
    hop8<<<gHop, B, 0, stream>>>(offs, edges, za, ys + (size_t)2 * NN6, zb);
    hop8<<<gHop, B, 0, stream>>>(offs, edges, zb, ys + (size_t)1 * NN6, za);
    hop8_final<<<gHop, B, 0, stream>>>(offs, edges, za, ys, out);
}

// Round 6
// 188.780 us; speedup vs baseline: 120.9830x; 1.0278x over previous
//
#include <hip/hip_runtime.h>

#define NN 50000
#define NE 800000
#define KH 4
#define FIN 6
#define FH 128
#define FO 6
#define ADIM 3
#define NN6 (NN * 6)
#define NBKT 196        // ceil(NN / 256) buckets of 256 node ids
#define EPB 2048        // edges per partition block
#define NPB 391         // ceil(NE / EPB)
#define CAP 5120        // LDS staging capacity per bucket
#define ROWMASK 0xFFFFFu
#define GDENSE 4096     // grid for dense1/proj2 (occupancy: 19% at 512 was the limiter)

typedef unsigned int u32;

struct __align__(8) Edge { u32 r; float w; };

// ---------------- K1: bucket histogram (col >> 8) ----------------
__global__ void bucket_hist(const int* __restrict__ col, u32* __restrict__ ghist) {
    __shared__ u32 h[NBKT];
    for (int t = threadIdx.x; t < NBKT; t += 256) h[t] = 0;
    __syncthreads();
    int base = blockIdx.x * EPB;
#pragma unroll
    for (int i = 0; i < EPB / 256; ++i) {
        int e = base + i * 256 + threadIdx.x;
        if (e < NE) atomicAdd(&h[((u32)col[e]) >> 8], 1u);
    }
    __syncthreads();
    for (int t = threadIdx.x; t < NBKT; t += 256)
        if (h[t]) atomicAdd(&ghist[t], h[t]);
}

// ---------------- K2: scan bucket counts -> bases/cursors ----------------
__global__ void bucket_scan(const u32* __restrict__ ghist, u32* __restrict__ bbase,
                            u32* __restrict__ bcur, int* __restrict__ offs) {
    __shared__ u32 sh[256];
    int t = threadIdx.x;
    u32 v = (t < NBKT) ? ghist[t] : 0;
    sh[t] = v;
    __syncthreads();
    for (int off = 1; off < 256; off <<= 1) {
        u32 u = (t >= off) ? sh[t - off] : 0;
        __syncthreads();
        sh[t] += u;
        __syncthreads();
    }
    if (t < NBKT) { bbase[t] = sh[t] - v; bcur[t] = sh[t] - v; }
    if (t == NBKT - 1) bbase[NBKT] = sh[t];
    if (t == 0) offs[NN] = NE;
}

// ---------------- K3: partition edges into bucket-grouped etmp (LDS-staged) ----------------
__global__ __launch_bounds__(256) void partition_kernel(
        const int* __restrict__ row, const int* __restrict__ col,
        const float* __restrict__ w, u32* __restrict__ bcur,
        Edge* __restrict__ etmp) {
    __shared__ u32 hcnt[NBKT];
    __shared__ u32 hloc[NBKT];
    __shared__ u32 hglb[NBKT];
    __shared__ u32 smeta[EPB];
    __shared__ float swt[EPB];
    __shared__ u32 sgid[EPB];
    __shared__ u32 sc[256];
    for (int t = threadIdx.x; t < NBKT; t += 256) hcnt[t] = 0;
    __syncthreads();
    int base = blockIdx.x * EPB;
    u32 m_[8]; float w_[8]; u32 b_[8]; u32 rk_[8]; int v_[8];
#pragma unroll
    for (int i = 0; i < 8; ++i) {
        int e = base + i * 256 + threadIdx.x;
        v_[i] = e < NE;
        if (v_[i]) {
            u32 c = (u32)col[e];
            u32 r = (u32)row[e];
            b_[i] = c >> 8;
            m_[i] = ((c & 255u) << 20) | r;
            w_[i] = w[e];
            rk_[i] = atomicAdd(&hcnt[b_[i]], 1u);
        }
    }
    __syncthreads();
    {   // exclusive scan of hcnt -> hloc
        int t = threadIdx.x;
        u32 v = (t < NBKT) ? hcnt[t] : 0;
        sc[t] = v;
        __syncthreads();
        for (int off = 1; off < 256; off <<= 1) {
            u32 u = (t >= off) ? sc[t - off] : 0;
            __syncthreads();
            sc[t] += u;
            __syncthreads();
        }
        if (t < NBKT) hloc[t] = sc[t] - v;
    }
    __syncthreads();
    for (int t = threadIdx.x; t < NBKT; t += 256)
        if (hcnt[t]) hglb[t] = atomicAdd(&bcur[t], hcnt[t]);
    __syncthreads();
#pragma unroll
    for (int i = 0; i < 8; ++i) if (v_[i]) {
        u32 slot = hloc[b_[i]] + rk_[i];
        smeta[slot] = m_[i];
        swt[slot] = w_[i];
        sgid[slot] = hglb[b_[i]] + rk_[i];
    }
    __syncthreads();
    int tot = NE - base; if (tot > EPB) tot = EPB;
    for (int s = threadIdx.x; s < tot; s += 256) {
        Edge ed; ed.r = smeta[s]; ed.w = swt[s];
        etmp[sgid[s]] = ed;
    }
}

// ---------------- K4: per-bucket CSR build + deg/dinv + offs (no global atomics) ----------------
__global__ __launch_bounds__(256) void bucket_csr(
        const u32* __restrict__ bbase, const Edge* __restrict__ etmp,
        Edge* __restrict__ edges, int* __restrict__ offs,
        float* __restrict__ dinv) {
    int b = blockIdx.x;
    int t = threadIdx.x;
    u32 s = bbase[b], e = bbase[b + 1];
    int cnt = (int)(e - s);
    int node0 = b << 8;
    int nloc = NN - node0; if (nloc > 256) nloc = 256;
    __shared__ u32 ncnt[256];
    __shared__ float nsum[256];
    __shared__ u32 ncur[256];
    __shared__ u32 sc[256];
    __shared__ Edge stage[CAP];   // 40 KB
    ncnt[t] = 0; nsum[t] = 0.f;
    __syncthreads();
    for (int i = t; i < cnt; i += 256) {
        Edge ed = etmp[s + i];
        u32 cl = ed.r >> 20;
        atomicAdd(&ncnt[cl], 1u);
        atomicAdd(&nsum[cl], ed.w);
    }
    __syncthreads();
    u32 v = ncnt[t];
    sc[t] = v;
    __syncthreads();
    for (int off = 1; off < 256; off <<= 1) {
        u32 u = (t >= off) ? sc[t - off] : 0;
        __syncthreads();
        sc[t] += u;
        __syncthreads();
    }
    u32 excl = sc[t] - v;
    ncur[t] = excl;
    if (t < nloc) {
        offs[node0 + t] = (int)(s + excl);
        float d = nsum[t];
        dinv[node0 + t] = d > 0.f ? rsqrtf(d) : 0.f;
    }
    __syncthreads();
    for (int i = t; i < cnt; i += 256) {
        Edge ed = etmp[s + i];
        u32 cl = ed.r >> 20;
        u32 slot = atomicAdd(&ncur[cl], 1u);
        Edge ce; ce.r = ed.r & ROWMASK; ce.w = ed.w;
        if (slot < CAP) stage[slot] = ce;
        else edges[s + slot] = ce;
    }
    __syncthreads();
    int lim = cnt < CAP ? cnt : CAP;
    for (int i = t; i < lim; i += 256) edges[s + i] = stage[i];
}

// ---------------- hop variant 1: normalize-in-place + first hop (xprev = x) ----------------
__global__ void hop8_norm(const int* __restrict__ offs, Edge* __restrict__ edges,
                          const float* __restrict__ dinv, const float* __restrict__ xprev,
                          float* __restrict__ xnext) {
    int t = blockIdx.x * blockDim.x + threadIdx.x;
    int n = t >> 3, j = t & 7;
    if (n >= NN) return;
    int s = offs[n], e = offs[n + 1];
    float dn = dinv[n];
    float a0 = 0.f, a1 = 0.f, a2 = 0.f, a3 = 0.f, a4 = 0.f, a5 = 0.f;
    for (int i = s + j; i < e; i += 8) {
        Edge ed = edges[i];
        float wn = ed.w * dn * dinv[ed.r];
        ed.w = wn;
        edges[i] = ed;                       // persist normalized weight for later hops
        const float* xr = xprev + (size_t)ed.r * 6;
        a0 += wn * xr[0]; a1 += wn * xr[1]; a2 += wn * xr[2];
        a3 += wn * xr[3]; a4 += wn * xr[4]; a5 += wn * xr[5];
    }
#pragma unroll
    for (int d = 1; d < 8; d <<= 1) {
        a0 += __shfl_xor(a0, d); a1 += __shfl_xor(a1, d); a2 += __shfl_xor(a2, d);
        a3 += __shfl_xor(a3, d); a4 += __shfl_xor(a4, d); a5 += __shfl_xor(a5, d);
    }
    if (j < 6) {
        float v = j == 0 ? a0 : j == 1 ? a1 : j == 2 ? a2 : j == 3 ? a3 : j == 4 ? a4 : a5;
        xnext[n * 6 + j] = v;
    }
}

// ---------------- hop: 8 lanes per node, shfl-reduce; xnext = yadd + A*xprev ----------------
__global__ void hop8(const int* __restrict__ offs, const Edge* __restrict__ edges,
                     const float* __restrict__ xprev, const float* __restrict__ yadd,
                     float* __restrict__ xnext) {
    int t = blockIdx.x * blockDim.x + threadIdx.x;
    int n = t >> 3, j = t & 7;
    if (n >= NN) return;
    int s = offs[n], e = offs[n + 1];
    float a0 = 0.f, a1 = 0.f, a2 = 0.f, a3 = 0.f, a4 = 0.f, a5 = 0.f;
    for (int i = s + j; i < e; i += 8) {
        Edge ed = edges[i];
        const float* xr = xprev + (size_t)ed.r * 6;
        a0 += ed.w * xr[0]; a1 += ed.w * xr[1]; a2 += ed.w * xr[2];
        a3 += ed.w * xr[3]; a4 += ed.w * xr[4]; a5 += ed.w * xr[5];
    }
#pragma unroll
    for (int d = 1; d < 8; d <<= 1) {
        a0 += __shfl_xor(a0, d); a1 += __shfl_xor(a1, d); a2 += __shfl_xor(a2, d);
        a3 += __shfl_xor(a3, d); a4 += __shfl_xor(a4, d); a5 += __shfl_xor(a5, d);
    }
    if (j < 6) {
        float v = j == 0 ? a0 : j == 1 ? a1 : j == 2 ? a2 : j == 3 ? a3 : j == 4 ? a4 : a5;
        if (yadd) v += yadd[n * 6 + j];
        xnext[n * 6 + j] = v;
    }
}

// ---------------- final hop fused with tanh/exp finalize ----------------
__global__ void hop8_final(const int* __restrict__ offs, const Edge* __restrict__ edges,
                           const float* __restrict__ xprev, const float* __restrict__ y0,
                           float* __restrict__ out) {
    int t = blockIdx.x * blockDim.x + threadIdx.x;
    int n = t >> 3, j = t & 7;
    if (n >= NN) return;
    int s = offs[n], e = offs[n + 1];
    float a0 = 0.f, a1 = 0.f, a2 = 0.f, a3 = 0.f, a4 = 0.f, a5 = 0.f;
    for (int i = s + j; i < e; i += 8) {
        Edge ed = edges[i];
        const float* xr = xprev + (size_t)ed.r * 6;
        a0 += ed.w * xr[0]; a1 += ed.w * xr[1]; a2 += ed.w * xr[2];
        a3 += ed.w * xr[3]; a4 += ed.w * xr[4]; a5 += ed.w * xr[5];
    }
#pragma unroll
    for (int d = 1; d < 8; d <<= 1) {
        a0 += __shfl_xor(a0, d); a1 += __shfl_xor(a1, d); a2 += __shfl_xor(a2, d);
        a3 += __shfl_xor(a3, d); a4 += __shfl_xor(a4, d); a5 += __shfl_xor(a5, d);
    }
    if (j < 6) {
        float v = j == 0 ? a0 : j == 1 ? a1 : j == 2 ? a2 : j == 3 ? a3 : j == 4 ? a4 : a5;
        v += y0[n * 6 + j];
        float tv = tanhf(v);
        if (j < ADIM) out[n * ADIM + j] = tv;
        else          out[NN * ADIM + n * ADIM + (j - ADIM)] = expf(2.f * tv);
    }
}

// ---------------- layer 1 fused dense (grid-stride) ----------------
__global__ void dense1_kernel(const float* __restrict__ x, const float* __restrict__ xs,
                              const float* __restrict__ W1, const float* __restrict__ b1,
                              float* __restrict__ acc1) {
    __shared__ float sW[(KH + 1) * FIN * FH];
    for (int t = threadIdx.x; t < (KH + 1) * FIN * FH; t += blockDim.x) sW[t] = W1[t];
    __syncthreads();
    int f = threadIdx.x & 127;
    int half = threadIdx.x >> 7;
    float bf = b1[f];
    for (int n = blockIdx.x * 2 + half; n < NN; n += gridDim.x * 2) {
        float s = bf;
        const float* xr = x + n * FIN;
#pragma unroll
        for (int c = 0; c < FIN; ++c) s += xr[c] * sW[c * FH + f];
#pragma unroll
        for (int k = 1; k <= KH; ++k) {
            const float* xk = xs + (size_t)(k - 1) * NN6 + n * 6;
            const float* wr = sW + k * FIN * FH;
#pragma unroll
            for (int c = 0; c < FIN; ++c) s += xk[c] * wr[c * FH + f];
        }
        acc1[(size_t)n * FH + f] = s > 0.f ? s : 0.f;
    }
}

// ---------------- layer 2 projections (grid-stride) ----------------
__global__ void proj2_kernel(const float* __restrict__ h, const float* __restrict__ W2,
                             const float* __restrict__ b2, float* __restrict__ ys) {
    __shared__ float sW[(KH + 1) * FH * FO];
    for (int t = threadIdx.x; t < (KH + 1) * FH * FO; t += blockDim.x) sW[t] = W2[t];
    __syncthreads();
    for (int idx = blockIdx.x * blockDim.x + threadIdx.x; idx < NN6;
         idx += gridDim.x * blockDim.x) {
        int n = idx / 6;
        int a = idx % 6;
        const float4* hr = (const float4*)(h + (size_t)n * FH);
        float s0 = b2[a], s1 = 0.f, s2 = 0.f, s3 = 0.f, s4 = 0.f;
#pragma unroll 8
        for (int c4 = 0; c4 < FH / 4; ++c4) {
            float4 hv = hr[c4];
            const float* w0 = sW + (c4 * 4) * FO + a;
#pragma unroll
            for (int j = 0; j < 4; ++j) {
                float hj = j == 0 ? hv.x : j == 1 ? hv.y : j == 2 ? hv.z : hv.w;
                s0 += hj * w0[j * FO];
                s1 += hj * w0[1 * FH * FO + j * FO];
                s2 += hj * w0[2 * FH * FO + j * FO];
                s3 += hj * w0[3 * FH * FO + j * FO];
                s4 += hj * w0[4 * FH * FO + j * FO];
            }
        }
        ys[idx] = s0;
        ys[1 * NN6 + idx] = s1;
        ys[2 * NN6 + idx] = s2;
        ys[3 * NN6 + idx] = s3;
        ys[4 * NN6 + idx] = s4;
    }
}

extern "C" void kernel_launch(void* const* d_in, const int* in_sizes, int n_in,
                              void* d_out, int out_size, void* d_ws, size_t ws_size,
                              hipStream_t stream) {
    const float* x  = (const float*)d_in[0];
    const int*   ei = (const int*)d_in[1];
    const float* ew = (const float*)d_in[2];
    const float* W1 = (const float*)d_in[3];
    const float* b1 = (const float*)d_in[4];
    const float* W2 = (const float*)d_in[5];
    const float* b2 = (const float*)d_in[6];
    float* out = (float*)d_out;

    const int* row = ei;
    const int* col = ei + NE;

    // workspace layout (8B-aligned Edge arrays first)
    Edge*  etmp  = (Edge*)d_ws;                 // NE
    Edge*  edges = etmp + NE;                   // NE
    u32*   ghist = (u32*)(edges + NE);          // NBKT
    u32*   bbase = ghist + NBKT;                // NBKT+1
    u32*   bcur  = bbase + NBKT + 1;            // NBKT
    int*   offs  = (int*)(bcur + NBKT);         // NN+1
    float* dinv  = (float*)(offs + NN + 1);     // NN
    float* xs    = dinv + NN;                   // KH*NN6
    float* acc1  = xs + (size_t)KH * NN6;       // NN*FH
    float* ys    = acc1 + (size_t)NN * FH;      // (KH+1)*NN6
    float* za    = ys + (size_t)(KH + 1) * NN6; // NN6
    float* zb    = za + NN6;                    // NN6

    const int B = 256;
    const int gHop = (NN * 8 + B - 1) / B;

    // ---- CSR build ----
    hipMemsetAsync(ghist, 0, NBKT * sizeof(u32), stream);
    bucket_hist<<<NPB, B, 0, stream>>>(col, ghist);
    bucket_scan<<<1, B, 0, stream>>>(ghist, bbase, bcur, offs);
    partition_kernel<<<NPB, B, 0, stream>>>(row, col, ew, bcur, etmp);
    bucket_csr<<<NBKT, B, 0, stream>>>(bbase, etmp, edges, offs, dinv);

    // ---- layer 1: hops on 6-wide input features (hop 1 fuses normalization) ----
    hop8_norm<<<gHop, B, 0, stream>>>(offs, edges, dinv, x, xs);
    for (int k = 2; k <= KH; ++k)
        hop8<<<gHop, B, 0, stream>>>(offs, edges,
                                     xs + (size_t)(k - 2) * NN6, nullptr,
                                     xs + (size_t)(k - 1) * NN6);
    dense1_kernel<<<GDENSE, B, 0, stream>>>(x, xs, W1, b1, acc1);

    // ---- layer 2: project first, then Horner on 6-wide ----
    proj2_kernel<<<GDENSE, B, 0, stream>>>(acc1, W2, b2, ys);
    hop8<<<gHop, B, 0, stream>>>(offs, edges, ys + (size_t)4 * NN6, ys + (size_t)3 * NN6, za);
    hop8<<<gHop, B, 0, stream>>>(offs, edges, za, ys + (size_t)2 * NN6, zb);
    hop8<<<gHop, B, 0, stream>>>(offs, edges, zb, ys + (size_t)1 * NN6, za);
    hop8_final<<<gHop, B, 0, stream>>>(offs, edges, za, ys, out);
}

// Round 7
// 164.470 us; speedup vs baseline: 138.8652x; 1.1478x over previous
//
#include <hip/hip_runtime.h>

#define NN 50000
#define NE 800000
#define KH 4
#define FIN 6
#define FH 128
#define FO 6
#define ADIM 3
#define NN6 (NN * 6)
#define NBKT 196        // ceil(NN / 256) buckets of 256 node ids
#define EPB 2048        // edges per partition block
#define NPB 391         // ceil(NE / EPB)
#define CAP 5120        // LDS staging capacity per bucket
#define ROWMASK 0xFFFFFu
#define GFUSE 2048      // grid for fused dense kernel (weights live in VGPRs, reloaded per block)

typedef unsigned int u32;

struct __align__(8) Edge { u32 r; float w; };

// ---------------- K1: bucket histogram (col >> 8) ----------------
__global__ void bucket_hist(const int* __restrict__ col, u32* __restrict__ ghist) {
    __shared__ u32 h[NBKT];
    for (int t = threadIdx.x; t < NBKT; t += 256) h[t] = 0;
    __syncthreads();
    int base = blockIdx.x * EPB;
#pragma unroll
    for (int i = 0; i < EPB / 256; ++i) {
        int e = base + i * 256 + threadIdx.x;
        if (e < NE) atomicAdd(&h[((u32)col[e]) >> 8], 1u);
    }
    __syncthreads();
    for (int t = threadIdx.x; t < NBKT; t += 256)
        if (h[t]) atomicAdd(&ghist[t], h[t]);
}

// ---------------- K2: scan bucket counts -> bases/cursors ----------------
__global__ void bucket_scan(const u32* __restrict__ ghist, u32* __restrict__ bbase,
                            u32* __restrict__ bcur, int* __restrict__ offs) {
    __shared__ u32 sh[256];
    int t = threadIdx.x;
    u32 v = (t < NBKT) ? ghist[t] : 0;
    sh[t] = v;
    __syncthreads();
    for (int off = 1; off < 256; off <<= 1) {
        u32 u = (t >= off) ? sh[t - off] : 0;
        __syncthreads();
        sh[t] += u;
        __syncthreads();
    }
    if (t < NBKT) { bbase[t] = sh[t] - v; bcur[t] = sh[t] - v; }
    if (t == NBKT - 1) bbase[NBKT] = sh[t];
    if (t == 0) offs[NN] = NE;
}

// ---------------- K3: partition edges into bucket-grouped etmp (LDS-staged) ----------------
__global__ __launch_bounds__(256) void partition_kernel(
        const int* __restrict__ row, const int* __restrict__ col,
        const float* __restrict__ w, u32* __restrict__ bcur,
        Edge* __restrict__ etmp) {
    __shared__ u32 hcnt[NBKT];
    __shared__ u32 hloc[NBKT];
    __shared__ u32 hglb[NBKT];
    __shared__ u32 smeta[EPB];
    __shared__ float swt[EPB];
    __shared__ u32 sgid[EPB];
    __shared__ u32 sc[256];
    for (int t = threadIdx.x; t < NBKT; t += 256) hcnt[t] = 0;
    __syncthreads();
    int base = blockIdx.x * EPB;
    u32 m_[8]; float w_[8]; u32 b_[8]; u32 rk_[8]; int v_[8];
#pragma unroll
    for (int i = 0; i < 8; ++i) {
        int e = base + i * 256 + threadIdx.x;
        v_[i] = e < NE;
        if (v_[i]) {
            u32 c = (u32)col[e];
            u32 r = (u32)row[e];
            b_[i] = c >> 8;
            m_[i] = ((c & 255u) << 20) | r;
            w_[i] = w[e];
            rk_[i] = atomicAdd(&hcnt[b_[i]], 1u);
        }
    }
    __syncthreads();
    {   // exclusive scan of hcnt -> hloc
        int t = threadIdx.x;
        u32 v = (t < NBKT) ? hcnt[t] : 0;
        sc[t] = v;
        __syncthreads();
        for (int off = 1; off < 256; off <<= 1) {
            u32 u = (t >= off) ? sc[t - off] : 0;
            __syncthreads();
            sc[t] += u;
            __syncthreads();
        }
        if (t < NBKT) hloc[t] = sc[t] - v;
    }
    __syncthreads();
    for (int t = threadIdx.x; t < NBKT; t += 256)
        if (hcnt[t]) hglb[t] = atomicAdd(&bcur[t], hcnt[t]);
    __syncthreads();
#pragma unroll
    for (int i = 0; i < 8; ++i) if (v_[i]) {
        u32 slot = hloc[b_[i]] + rk_[i];
        smeta[slot] = m_[i];
        swt[slot] = w_[i];
        sgid[slot] = hglb[b_[i]] + rk_[i];
    }
    __syncthreads();
    int tot = NE - base; if (tot > EPB) tot = EPB;
    for (int s = threadIdx.x; s < tot; s += 256) {
        Edge ed; ed.r = smeta[s]; ed.w = swt[s];
        etmp[sgid[s]] = ed;
    }
}

// ---------------- K4: per-bucket CSR build + deg/dinv + offs (no global atomics) ----------------
__global__ __launch_bounds__(256) void bucket_csr(
        const u32* __restrict__ bbase, const Edge* __restrict__ etmp,
        Edge* __restrict__ edges, int* __restrict__ offs,
        float* __restrict__ dinv) {
    int b = blockIdx.x;
    int t = threadIdx.x;
    u32 s = bbase[b], e = bbase[b + 1];
    int cnt = (int)(e - s);
    int node0 = b << 8;
    int nloc = NN - node0; if (nloc > 256) nloc = 256;
    __shared__ u32 ncnt[256];
    __shared__ float nsum[256];
    __shared__ u32 ncur[256];
    __shared__ u32 sc[256];
    __shared__ Edge stage[CAP];   // 40 KB
    ncnt[t] = 0; nsum[t] = 0.f;
    __syncthreads();
    for (int i = t; i < cnt; i += 256) {
        Edge ed = etmp[s + i];
        u32 cl = ed.r >> 20;
        atomicAdd(&ncnt[cl], 1u);
        atomicAdd(&nsum[cl], ed.w);
    }
    __syncthreads();
    u32 v = ncnt[t];
    sc[t] = v;
    __syncthreads();
    for (int off = 1; off < 256; off <<= 1) {
        u32 u = (t >= off) ? sc[t - off] : 0;
        __syncthreads();
        sc[t] += u;
        __syncthreads();
    }
    u32 excl = sc[t] - v;
    ncur[t] = excl;
    if (t < nloc) {
        offs[node0 + t] = (int)(s + excl);
        float d = nsum[t];
        dinv[node0 + t] = d > 0.f ? rsqrtf(d) : 0.f;
    }
    __syncthreads();
    for (int i = t; i < cnt; i += 256) {
        Edge ed = etmp[s + i];
        u32 cl = ed.r >> 20;
        u32 slot = atomicAdd(&ncur[cl], 1u);
        Edge ce; ce.r = ed.r & ROWMASK; ce.w = ed.w;
        if (slot < CAP) stage[slot] = ce;
        else edges[s + slot] = ce;
    }
    __syncthreads();
    int lim = cnt < CAP ? cnt : CAP;
    for (int i = t; i < lim; i += 256) edges[s + i] = stage[i];
}

// ---------------- hop variant 1: normalize-in-place + first hop (xprev = x, stride 6) ----------------
__global__ void hop8_norm(const int* __restrict__ offs, Edge* __restrict__ edges,
                          const float* __restrict__ dinv, const float* __restrict__ xprev,
                          float* __restrict__ xnext) {
    int t = blockIdx.x * blockDim.x + threadIdx.x;
    int n = t >> 3, j = t & 7;
    if (n >= NN) return;
    int s = offs[n], e = offs[n + 1];
    float dn = dinv[n];
    float a0 = 0.f, a1 = 0.f, a2 = 0.f, a3 = 0.f, a4 = 0.f, a5 = 0.f;
    for (int i = s + j; i < e; i += 8) {
        Edge ed = edges[i];
        float wn = ed.w * dn * dinv[ed.r];
        ed.w = wn;
        edges[i] = ed;                       // persist normalized weight for later hops
        const float* xr = xprev + (size_t)ed.r * 6;
        a0 += wn * xr[0]; a1 += wn * xr[1]; a2 += wn * xr[2];
        a3 += wn * xr[3]; a4 += wn * xr[4]; a5 += wn * xr[5];
    }
#pragma unroll
    for (int d = 1; d < 8; d <<= 1) {
        a0 += __shfl_xor(a0, d); a1 += __shfl_xor(a1, d); a2 += __shfl_xor(a2, d);
        a3 += __shfl_xor(a3, d); a4 += __shfl_xor(a4, d); a5 += __shfl_xor(a5, d);
    }
    if (j < 6) {
        float v = j == 0 ? a0 : j == 1 ? a1 : j == 2 ? a2 : j == 3 ? a3 : j == 4 ? a4 : a5;
        xnext[n * 6 + j] = v;
    }
}

// ---------------- hop: 8 lanes/node; xnext = yadd(ys-layout) + A * xprev(stride xst, offset xof) ----------------
__global__ void hop8(const int* __restrict__ offs, const Edge* __restrict__ edges,
                     const float* __restrict__ xprev, int xst, int xof,
                     const float* __restrict__ yadd,
                     float* __restrict__ xnext) {
    int t = blockIdx.x * blockDim.x + threadIdx.x;
    int n = t >> 3, j = t & 7;
    if (n >= NN) return;
    int s = offs[n], e = offs[n + 1];
    float a0 = 0.f, a1 = 0.f, a2 = 0.f, a3 = 0.f, a4 = 0.f, a5 = 0.f;
    for (int i = s + j; i < e; i += 8) {
        Edge ed = edges[i];
        const float* xr = xprev + (size_t)ed.r * xst + xof;
        a0 += ed.w * xr[0]; a1 += ed.w * xr[1]; a2 += ed.w * xr[2];
        a3 += ed.w * xr[3]; a4 += ed.w * xr[4]; a5 += ed.w * xr[5];
    }
#pragma unroll
    for (int d = 1; d < 8; d <<= 1) {
        a0 += __shfl_xor(a0, d); a1 += __shfl_xor(a1, d); a2 += __shfl_xor(a2, d);
        a3 += __shfl_xor(a3, d); a4 += __shfl_xor(a4, d); a5 += __shfl_xor(a5, d);
    }
    if (j < 6) {
        float v = j == 0 ? a0 : j == 1 ? a1 : j == 2 ? a2 : j == 3 ? a3 : j == 4 ? a4 : a5;
        if (yadd) v += yadd[(size_t)n * 30 + j];   // ys node-major [n][5][6], caller pre-offsets k*6
        xnext[n * 6 + j] = v;
    }
}

// ---------------- final hop fused with tanh/exp finalize ----------------
__global__ void hop8_final(const int* __restrict__ offs, const Edge* __restrict__ edges,
                           const float* __restrict__ xprev, const float* __restrict__ y0,
                           float* __restrict__ out) {
    int t = blockIdx.x * blockDim.x + threadIdx.x;
    int n = t >> 3, j = t & 7;
    if (n >= NN) return;
    int s = offs[n], e = offs[n + 1];
    float a0 = 0.f, a1 = 0.f, a2 = 0.f, a3 = 0.f, a4 = 0.f, a5 = 0.f;
    for (int i = s + j; i < e; i += 8) {
        Edge ed = edges[i];
        const float* xr = xprev + (size_t)ed.r * 6;
        a0 += ed.w * xr[0]; a1 += ed.w * xr[1]; a2 += ed.w * xr[2];
        a3 += ed.w * xr[3]; a4 += ed.w * xr[4]; a5 += ed.w * xr[5];
    }
#pragma unroll
    for (int d = 1; d < 8; d <<= 1) {
        a0 += __shfl_xor(a0, d); a1 += __shfl_xor(a1, d); a2 += __shfl_xor(a2, d);
        a3 += __shfl_xor(a3, d); a4 += __shfl_xor(a4, d); a5 += __shfl_xor(a5, d);
    }
    if (j < 6) {
        float v = j == 0 ? a0 : j == 1 ? a1 : j == 2 ? a2 : j == 3 ? a3 : j == 4 ? a4 : a5;
        v += y0[(size_t)n * 30 + j];               // ys node-major, k=0 slice
        float tv = tanhf(v);
        if (j < ADIM) out[n * ADIM + j] = tv;
        else          out[NN * ADIM + n * ADIM + (j - ADIM)] = expf(2.f * tv);
    }
}

// ---------------- fused dense: ys[n][k][a] = (relu(sum xs@W1 + b1)) @ W2[k] (+b2 k=0) ----------------
// Weights in VGPRs (f / (k,a,q) roles fixed per thread across grid-stride iters).
__global__ __launch_bounds__(256) void fused_dense_kernel(
        const float* __restrict__ x, const float* __restrict__ xs,
        const float* __restrict__ W1, const float* __restrict__ b1,
        const float* __restrict__ W2, const float* __restrict__ b2,
        float* __restrict__ ys) {
    __shared__ float sin_[2][32];
    __shared__ float sh[2][128];
    int t = threadIdx.x;
    int f = t & 127, half = t >> 7;
    float w1r[30];
#pragma unroll
    for (int i = 0; i < 30; ++i) w1r[i] = W1[i * FH + f];
    float b1r = b1[f];
    // phase-B role: 240 active threads = 2 nodes x 30 (k,a) x 4 quarters
    bool bact = t < 240;
    int bn = t / 120;
    int rem = t % 120;
    int ka = rem >> 2;          // 0..29
    int q  = rem & 3;
    int k2 = ka / 6, a2 = ka - k2 * 6;
    float w2r[32];
#pragma unroll
    for (int i = 0; i < 32; ++i)
        w2r[i] = bact ? W2[((size_t)k2 * FH + q * 32 + i) * FO + a2] : 0.f;
    float badd = (bact && k2 == 0 && q == 0) ? b2[a2] : 0.f;

    for (int n0 = blockIdx.x * 2; n0 < NN; n0 += GFUSE * 2) {
        // stage 60 input floats (x row + 4 xs rows per node)
        if (t < 60) {
            int nn = t / 30, c = t - nn * 30;
            int n = n0 + nn;
            float v;
            if (c < 6) v = x[n * 6 + c];
            else       v = xs[(size_t)((c - 6) / 6) * NN6 + n * 6 + (c - 6) % 6];
            sin_[nn][c] = v;
        }
        __syncthreads();
        // phase A: h = relu(b1 + sum_i in[i]*W1col[i])
        {
            float s = b1r;
#pragma unroll
            for (int i = 0; i < 30; ++i) s += sin_[half][i] * w1r[i];
            sh[half][f] = s > 0.f ? s : 0.f;
        }
        __syncthreads();
        // phase B: ys[n][ka] = sum_c h[c]*W2[k][c][a], 4-lane split over c
        if (bact) {
            float s = badd;
            const float* hr = &sh[bn][q * 32];
#pragma unroll
            for (int i = 0; i < 32; ++i) s += hr[i] * w2r[i];
            s += __shfl_xor(s, 1);
            s += __shfl_xor(s, 2);
            if (q == 0) ys[(size_t)(n0 + bn) * 30 + ka] = s;
        }
        // next-iter stage (writes sin_) is fenced from phase A by the post-stage barrier;
        // phase B (reads sh) is fenced from next phase A by the same barrier.
    }
}

extern "C" void kernel_launch(void* const* d_in, const int* in_sizes, int n_in,
                              void* d_out, int out_size, void* d_ws, size_t ws_size,
                              hipStream_t stream) {
    const float* x  = (const float*)d_in[0];
    const int*   ei = (const int*)d_in[1];
    const float* ew = (const float*)d_in[2];
    const float* W1 = (const float*)d_in[3];
    const float* b1 = (const float*)d_in[4];
    const float* W2 = (const float*)d_in[5];
    const float* b2 = (const float*)d_in[6];
    float* out = (float*)d_out;

    const int* row = ei;
    const int* col = ei + NE;

    // workspace layout (8B-aligned Edge arrays first)
    Edge*  etmp  = (Edge*)d_ws;                 // NE
    Edge*  edges = etmp + NE;                   // NE
    u32*   ghist = (u32*)(edges + NE);          // NBKT
    u32*   bbase = ghist + NBKT;                // NBKT+1
    u32*   bcur  = bbase + NBKT + 1;            // NBKT
    int*   offs  = (int*)(bcur + NBKT);         // NN+1
    float* dinv  = (float*)(offs + NN + 1);     // NN
    float* xs    = dinv + NN;                   // KH*NN6
    float* ys    = xs + (size_t)KH * NN6;       // NN*30 (node-major [n][5][6])
    float* za    = ys + (size_t)NN * 30;        // NN6
    float* zb    = za + NN6;                    // NN6

    const int B = 256;
    const int gHop = (NN * 8 + B - 1) / B;

    // ---- CSR build ----
    hipMemsetAsync(ghist, 0, NBKT * sizeof(u32), stream);
    bucket_hist<<<NPB, B, 0, stream>>>(col, ghist);
    bucket_scan<<<1, B, 0, stream>>>(ghist, bbase, bcur, offs);
    partition_kernel<<<NPB, B, 0, stream>>>(row, col, ew, bcur, etmp);
    bucket_csr<<<NBKT, B, 0, stream>>>(bbase, etmp, edges, offs, dinv);

    // ---- layer 1: hops on 6-wide input features (hop 1 fuses normalization) ----
    hop8_norm<<<gHop, B, 0, stream>>>(offs, edges, dinv, x, xs);
    for (int k = 2; k <= KH; ++k)
        hop8<<<gHop, B, 0, stream>>>(offs, edges,
                                     xs + (size_t)(k - 2) * NN6, 6, 0, nullptr,
                                     xs + (size_t)(k - 1) * NN6);

    // ---- fused dense1 + relu + proj2 (no acc1 round-trip) ----
    fused_dense_kernel<<<GFUSE, B, 0, stream>>>(x, xs, W1, b1, W2, b2, ys);

    // ---- layer 2 Horner on 6-wide ----
    // za = y3 + A*y4   (y4 is strided slice of node-major ys)
    hop8<<<gHop, B, 0, stream>>>(offs, edges, ys, 30, 24, ys + 18, za);
    hop8<<<gHop, B, 0, stream>>>(offs, edges, za, 6, 0, ys + 12, zb);
    hop8<<<gHop, B, 0, stream>>>(offs, edges, zb, 6, 0, ys + 6, za);
    hop8_final<<<gHop, B, 0, stream>>>(offs, edges, za, ys, out);
}